// Round 4
// baseline (4636.422 us; speedup 1.0000x reference)
//
#include <hip/hip_runtime.h>

#define TT 12
#define NN 512
#define CD 128
#define SLICE (CD*NN)   // 65536
#define NSL 768         // B*T

// ---------------- start conv: X[sl][d][n] = Wst[d][:]·x0[b][:][n][t] + bst[d] ----------------
__global__ __launch_bounds__(256) void k_start(const float* __restrict__ x0,
        const float* __restrict__ Wst, const float* __restrict__ bst,
        float* __restrict__ X, const int s0){
    int idx = blockIdx.x*256 + threadIdx.x;          // sl*65536 + d*512 + n
    int n = idx & (NN-1);
    int d = (idx>>9) & (CD-1);
    int sl = idx >> 16;
    int s = s0 + sl;
    int b = s/TT, t = s - b*TT;
    int base = (b*2*NN + n)*TT + t;                  // x0[b][0][n][t]
    float v0 = x0[base];
    float v1 = x0[base + NN*TT];                     // ci=1
    X[idx] = Wst[2*d]*v0 + Wst[2*d+1]*v1 + bst[d];
}

// ---------------- skip conv, accumulates into out[s][n][o]; step==2 applies output BN ----------------
__global__ __launch_bounds__(256) void k_skip(const float* __restrict__ X,
        const float* __restrict__ W, const float* __restrict__ bias,
        float* __restrict__ out,
        const float* __restrict__ og, const float* __restrict__ obt,
        const float* __restrict__ om, const float* __restrict__ ov,
        const int step, const int s0){
    __shared__ float Lt[16*68];   // [k=c][n 64 (+4 pad)]
    __shared__ float Rt[16*68];   // [k=c][o 64 (+4 pad)]
    const int t   = threadIdx.x;
    const int sl  = blockIdx.x >> 4;
    const int r   = blockIdx.x & 15;
    const int nb  = (r >> 1) * 64;
    const int obk = (r & 1) * 64;
    const int tx = t & 15, ty = t >> 4;   // tx: o-group, ty: n-group
    const float* Xs = X + (size_t)sl*SLICE;
    float acc[4][4] = {};                 // [n][o]
    for (int cb = 0; cb < CD; cb += 16) {
        {   int k = t >> 4, n4 = (t & 15)*4;
            *(float4*)(Lt + k*68 + n4) = *(const float4*)(Xs + (cb+k)*NN + nb + n4); }
        {   int o = t >> 2, kg = (t & 3)*4;
            float4 w4 = *(const float4*)(W + (obk + o)*CD + cb + kg);   // FIX: +obk
            Rt[(kg+0)*68 + o] = w4.x; Rt[(kg+1)*68 + o] = w4.y;
            Rt[(kg+2)*68 + o] = w4.z; Rt[(kg+3)*68 + o] = w4.w; }
        __syncthreads();
        #pragma unroll
        for (int k=0;k<16;k++){
            float4 a4 = *(const float4*)(Lt + k*68 + ty*4);
            float4 b4 = *(const float4*)(Rt + k*68 + tx*4);
            float av[4] = {a4.x,a4.y,a4.z,a4.w};
            float bv[4] = {b4.x,b4.y,b4.z,b4.w};
            #pragma unroll
            for (int i=0;i<4;i++)
                #pragma unroll
                for (int j=0;j<4;j++) acc[i][j] += av[i]*bv[j];
        }
        __syncthreads();
    }
    float bz[4], ao[4], co[4];
    #pragma unroll
    for (int j=0;j<4;j++){
        int o = obk + tx*4 + j;
        bz[j] = bias[o];
        if (step == 2) {
            float inv = og[o] * rsqrtf(ov[o] + 1e-5f);
            ao[j] = inv; co[j] = obt[o] - om[o]*inv;
        }
    }
    #pragma unroll
    for (int i=0;i<4;i++){
        int n = nb + ty*4 + i;
        float* po = out + (size_t)(s0+sl)*SLICE + n*CD + obk + tx*4;
        float v[4];
        #pragma unroll
        for (int j=0;j<4;j++) v[j] = acc[i][j] + bz[j];
        if (step > 0) {
            float4 pv = *(const float4*)po;
            v[0]+=pv.x; v[1]+=pv.y; v[2]+=pv.z; v[3]+=pv.w;
        }
        if (step == 2) {
            #pragma unroll
            for (int j=0;j<4;j++) v[j] = ao[j]*v[j] + co[j];
        }
        float4 w4; w4.x=v[0]; w4.y=v[1]; w4.z=v[2]; w4.w=v[3];
        *(float4*)po = w4;
    }
}

// ---------------- node conv: DST[sl][c][w] = sum_v SRC[sl][c][v] * adj[v][w] ----------------
__global__ __launch_bounds__(256) void k_nconv(const float* __restrict__ SRC,
        const float* __restrict__ adj, float* __restrict__ DST){
    __shared__ float Lt[16*68];   // [k=v][c 64 (+4)]
    __shared__ float Rt[16*68];   // [k=v][w 64 (+4)]
    const int t  = threadIdx.x;
    const int sl = blockIdx.x >> 4;
    const int r  = blockIdx.x & 15;
    const int cb = (r >> 3) * 64;
    const int wb = (r & 7) * 64;
    const int tx = t & 15, ty = t >> 4;   // tx: w-group, ty: c-group
    const float* Ss = SRC + (size_t)sl*SLICE;
    float acc[4][4] = {};                 // [c][w]
    for (int vb = 0; vb < NN; vb += 16) {
        {   int c = t >> 2, kg = (t & 3)*4;
            float4 x4 = *(const float4*)(Ss + (cb+c)*NN + vb + kg);
            Lt[(kg+0)*68 + c] = x4.x; Lt[(kg+1)*68 + c] = x4.y;
            Lt[(kg+2)*68 + c] = x4.z; Lt[(kg+3)*68 + c] = x4.w; }
        {   int k = t >> 4, w4i = (t & 15)*4;
            *(float4*)(Rt + k*68 + w4i) = *(const float4*)(adj + (vb+k)*NN + wb + w4i); }
        __syncthreads();
        #pragma unroll
        for (int k=0;k<16;k++){
            float4 a4 = *(const float4*)(Lt + k*68 + ty*4);
            float4 b4 = *(const float4*)(Rt + k*68 + tx*4);
            float av[4] = {a4.x,a4.y,a4.z,a4.w};
            float bv[4] = {b4.x,b4.y,b4.z,b4.w};
            #pragma unroll
            for (int i=0;i<4;i++)
                #pragma unroll
                for (int j=0;j<4;j++) acc[i][j] += av[i]*bv[j];
        }
        __syncthreads();
    }
    #pragma unroll
    for (int i=0;i<4;i++){
        float* pd = DST + (size_t)sl*SLICE + (cb+ty*4+i)*NN + wb + tx*4;
        float4 w4; w4.x=acc[i][0]; w4.y=acc[i][1]; w4.z=acc[i][2]; w4.w=acc[i][3];
        *(float4*)pd = w4;
    }
}

// ---------------- gc conv (K=384 over [X,X1,X2]) + gc BN + residual + step BN, X updated in place ----------------
__global__ __launch_bounds__(256) void k_gc(float* X,
        const float* __restrict__ X1, const float* __restrict__ X2,
        const float* __restrict__ W, const float* __restrict__ bias,
        const float* __restrict__ gg, const float* __restrict__ gb,
        const float* __restrict__ gm, const float* __restrict__ gv,
        const float* __restrict__ bg, const float* __restrict__ bb,
        const float* __restrict__ bm, const float* __restrict__ bv){
    __shared__ float Lt[16*132];  // [k][o 128 (+4)]
    __shared__ float Rt[16*36];   // [k][n 32 (+4)]
    const int t  = threadIdx.x;
    const int sl = blockIdx.x >> 4;
    const int nb = (blockIdx.x & 15) * 32;
    const int tx = t & 7, ty = t >> 3;   // tx: n-group(8), ty: o-group(32)
    float acc[4][4] = {};                // [o][n]
    const float* srcs[3] = { X + (size_t)sl*SLICE, X1 + (size_t)sl*SLICE, X2 + (size_t)sl*SLICE };
    for (int ph = 0; ph < 3; ph++){
        const float* S  = srcs[ph];
        const float* Wp = W + ph*CD;     // W[o][ph*128 + c] = Wp[o*384 + c]
        for (int cb = 0; cb < CD; cb += 16){
            {   int o = t >> 1, kg = (t & 1)*8;
                const float* p = Wp + o*384 + cb + kg;
                float4 wa = *(const float4*)(p);
                float4 wb4 = *(const float4*)(p + 4);
                Lt[(kg+0)*132 + o] = wa.x;  Lt[(kg+1)*132 + o] = wa.y;
                Lt[(kg+2)*132 + o] = wa.z;  Lt[(kg+3)*132 + o] = wa.w;
                Lt[(kg+4)*132 + o] = wb4.x; Lt[(kg+5)*132 + o] = wb4.y;
                Lt[(kg+6)*132 + o] = wb4.z; Lt[(kg+7)*132 + o] = wb4.w; }
            if (t < 128){
                int k = t >> 3, n4 = (t & 7)*4;
                *(float4*)(Rt + k*36 + n4) = *(const float4*)(S + (cb+k)*NN + nb + n4); }
            __syncthreads();
            #pragma unroll
            for (int k=0;k<16;k++){
                float4 a4 = *(const float4*)(Lt + k*132 + ty*4);
                float4 b4 = *(const float4*)(Rt + k*36 + tx*4);
                float av[4] = {a4.x,a4.y,a4.z,a4.w};
                float bv[4] = {b4.x,b4.y,b4.z,b4.w};
                #pragma unroll
                for (int i=0;i<4;i++)
                    #pragma unroll
                    for (int j=0;j<4;j++) acc[i][j] += av[i]*bv[j];
            }
            __syncthreads();
        }
    }
    #pragma unroll
    for (int i=0;i<4;i++){
        int o = ty*4 + i;
        float h0  = bias[o];
        float ig  = gg[o] * rsqrtf(gv[o] + 1e-5f);
        float cg_ = gb[o] - gm[o]*ig;
        float ib  = bg[o] * rsqrtf(bv[o] + 1e-5f);
        float cb_ = bb[o] - bm[o]*ib;
        float* px = X + (size_t)sl*SLICE + o*NN + nb + tx*4;
        float4 rv = *(const float4*)px;
        float res[4] = {rv.x, rv.y, rv.z, rv.w};
        float v[4];
        #pragma unroll
        for (int j=0;j<4;j++)
            v[j] = ib*( ig*(acc[i][j] + h0) + cg_ + res[j] ) + cb_;
        float4 w4; w4.x=v[0]; w4.y=v[1]; w4.z=v[2]; w4.w=v[3];
        *(float4*)px = w4;
    }
}

extern "C" void kernel_launch(void* const* d_in, const int* in_sizes, int n_in,
                              void* d_out, int out_size, void* d_ws, size_t ws_size,
                              hipStream_t stream) {
    const float* x0   = (const float*)d_in[0];
    const float* adj  = (const float*)d_in[1];
    const float* Wst  = (const float*)d_in[2];
    const float* bst  = (const float*)d_in[3];
    const float* Wsk  = (const float*)d_in[4];
    const float* bsk  = (const float*)d_in[5];
    const float* Wgc  = (const float*)d_in[6];
    const float* bgc  = (const float*)d_in[7];
    const float* gg   = (const float*)d_in[8];
    const float* gb   = (const float*)d_in[9];
    const float* gm   = (const float*)d_in[10];
    const float* gv   = (const float*)d_in[11];
    const float* bg   = (const float*)d_in[12];
    const float* bb   = (const float*)d_in[13];
    const float* bm   = (const float*)d_in[14];
    const float* bv   = (const float*)d_in[15];
    const float* og   = (const float*)d_in[16];
    const float* obt  = (const float*)d_in[17];
    const float* om   = (const float*)d_in[18];
    const float* ov   = (const float*)d_in[19];
    float* out = (float*)d_out;            // [b][t][n][d] == [s][n][o]

    // Chunk the 768 independent (b,t) slices so 3 fp32 [SC][128][512] scratch
    // tensors fit in ws_size.
    static const int divs[] = {768,384,256,192,128,96,64,48,32,24,16,12,8,6,4,3,2,1};
    const size_t perSlice = (size_t)SLICE * 4;     // 256 KB per slice per buffer
    int SC = 1;
    for (int di = 0; di < 18; di++) {
        if (3 * (size_t)divs[di] * perSlice <= ws_size) { SC = divs[di]; break; }
    }
    float* X  = (float*)d_ws;
    float* X1 = X  + (size_t)SC*SLICE;
    float* X2 = X1 + (size_t)SC*SLICE;

    for (int s0 = 0; s0 < NSL; s0 += SC) {
        k_start<<<SC*(SLICE/256), 256, 0, stream>>>(x0, Wst, bst, X, s0);
        for (int i = 0; i < 3; i++) {
            k_skip<<<SC*16, 256, 0, stream>>>(X, Wsk + i*CD*CD, bsk + i*CD, out,
                                              og, obt, om, ov, i, s0);
            if (i == 2) break;
            k_nconv<<<SC*16, 256, 0, stream>>>(X,  adj, X1);
            k_nconv<<<SC*16, 256, 0, stream>>>(X1, adj, X2);
            k_gc<<<SC*16, 256, 0, stream>>>(X, X1, X2,
                Wgc + i*CD*384, bgc + i*CD,
                gg + i*CD, gb + i*CD, gm + i*CD, gv + i*CD,
                bg + i*CD, bb + i*CD, bm + i*CD, bv + i*CD);
        }
    }
}